// Round 10
// baseline (177.450 us; speedup 1.0000x reference)
//
#include <hip/hip_runtime.h>

// EulerIntegrator: B=4096, D=1024, R=256, steps=8, dt=0.01
// R10: phase-overlap via 2 co-resident blocks/CU. 512-thr blocks (8 waves),
// grid 512, 8 real rows/block (rows 8-15 of the 16-row MFMA tile are zeroed
// garbage). 49.9 KB LDS/block (f->v sequential staging through one A-buffer,
// single p^2 buffer + 2 barriers/step, 2-pass epilogue aliasing A-buffer).
// Each wave owns TWO nt columns (w, w+8); wu for both in regs (64 VGPR).
// VGPR budget 128 (16 waves/CU) -- no e-fold (it cannot fit; R7/R9 lesson).
// Fragment traffic doubles (512 blocks x 1MB) -- accepted per R9's null
// (fragment reads are not BW-bound; euler is phase-latency bound).
// Recurrence: P <- P + dt*(FU - (P*P)@WU) in [B,256];
//   v_fin = v0 + s*dt*f - dt*(Q1@W), x_fin = x0 + s*dt*v0 + T*dt^2*f - dt^2*(Q2@W)

#define BB 4096
#define DD 1024
#define RR 256
#define DT 0.01f

typedef __attribute__((ext_vector_type(8))) short short8;   // 8 bf16 = 4 VGPRs
typedef __attribute__((ext_vector_type(4))) short short4v;  // 4 bf16 = 8B
typedef __attribute__((ext_vector_type(4))) float floatx4;  // MFMA acc

static __device__ inline unsigned short f2bf(float f) {
    union { float f; unsigned int u; } c; c.f = f;
    unsigned int u = c.u;
    u += 0x7fffu + ((u >> 16) & 1u);   // round-to-nearest-even
    return (unsigned short)(u >> 16);
}

// Fragment layout (B-operand, 16x16x32): frag (kt,nt), lane l, elem j holds
// M[kt*32 + (l>>4)*8 + j][nt*16 + (l&15)]; short index = frag*512 + l*8 + j.
// Blocks 0..63: pack U (32x16). 64..127: pack W (8x64). 128..383: WU rows.
__global__ __launch_bounds__(1024)
void pack_kernel(const float* __restrict__ U, const float* __restrict__ W,
                 short* __restrict__ Up, short* __restrict__ Wp,
                 short* __restrict__ WUp) {
    __shared__ float4 red[16][64];   // WU blocks only
    const int b = blockIdx.x;
    const int tid = threadIdx.x;

    if (b < 128) {
        const bool isU = (b < 64);
        const float* M = isU ? U : W;
        short* P = isU ? Up : Wp;
        const int ld = isU ? RR : DD;
        int t = (isU ? b : b - 64) * 1024 + tid;   // 0..65535
        int S = t * 4;                              // short index of first elem
        int j0   = S & 7;
        int lane = (S >> 3) & 63;
        int frag = S >> 9;
        int nl = lane & 15, kq = lane >> 4;
        int kt, nt;
        if (isU) { kt = frag >> 4; nt = frag & 15; }
        else     { kt = frag >> 6; nt = frag & 63; }
        int k0 = kt * 32 + kq * 8 + j0;
        int n  = nt * 16 + nl;
        short4v o;
#pragma unroll
        for (int jj = 0; jj < 4; jj++)
            o[jj] = (short)f2bf(M[(long)(k0 + jj) * ld + n]);
        *(short4v*)(P + S) = o;                     // coalesced 8B write
    } else {
        // WU[i][j] = sum_k W[i][k]*U[k][j]; i = b-128.
        const int i  = b - 128;
        const int ks = tid >> 6;                    // 0..15
        const int j4 = tid & 63;
        const float4* U4 = (const float4*)U;
        const float*  wr = W + (long)i * DD + ks * 64;
        float4 acc = {0.f, 0.f, 0.f, 0.f};
#pragma unroll 8
        for (int m = 0; m < 64; m++) {
            float w = wr[m];                        // wave-uniform
            float4 u = U4[(ks * 64 + m) * 64 + j4]; // 1KB/wave coalesced
            acc.x += w * u.x; acc.y += w * u.y;
            acc.z += w * u.z; acc.w += w * u.w;
        }
        red[ks][j4] = acc;
        __syncthreads();
        if (tid < 64) {
            float4 a = red[0][tid];
#pragma unroll
            for (int s = 1; s < 16; s++) {
                float4 r = red[s][tid];
                a.x += r.x; a.y += r.y; a.z += r.z; a.w += r.w;
            }
            int ktw = i >> 5, kqw = (i >> 3) & 3, jjw = i & 7;
            float av[4] = {a.x, a.y, a.z, a.w};
#pragma unroll
            for (int c = 0; c < 4; c++) {
                int j = 4 * tid + c;
                int nt = j >> 4, nl = j & 15;
                WUp[(((ktw * 16 + nt) * 64) + kqw * 16 + nl) * 8 + jjw] =
                    (short)f2bf(av[c]);
            }
        }
    }
}

__global__ __launch_bounds__(512, 4)
void euler_kernel(const float* __restrict__ x0,
                  const float* __restrict__ v0,
                  const float* __restrict__ force,
                  const short8* __restrict__ Up,
                  const short8* __restrict__ Wp,
                  const short8* __restrict__ WUp,
                  const int* __restrict__ steps_p,
                  float* __restrict__ out) {
    // LDS 24960 shorts = 49,920 B -> 2 blocks/CU.
    //   A-region bytes [0,33024): va bf16 [16][1032] (rows 0-7 data, 8-15
    //     zeroed) for f then v; epilogue aliases as s f32 [8][1032].
    //   q1 shorts [16512..20735]: [16][264]  p^2 buffer / final Q1
    //   q2 shorts [20736..24959]: [16][264]  final Q2
    __shared__ __align__(16) short smem[24960];

    const int tid  = threadIdx.x;
    const int w    = tid >> 6;          // 0..7
    const int lane = tid & 63;
    const int nl   = lane & 15;
    const int quad = lane >> 4;
    const int row0 = blockIdx.x * 8;
    const int steps = steps_p[0];
    const float sdt  = steps * DT;
    const float tdt2 = 0.5f * (float)(steps * (steps - 1)) * DT * DT;

    short (*va)[1032] = (short(*)[1032])smem;
    short (*q1)[264]  = (short(*)[264])(smem + 16512);
    short (*q2)[264]  = (short(*)[264])(smem + 20736);

    const float4* v04 = (const float4*)v0;
    const float4* f44 = (const float4*)force;
    const float4* x4  = (const float4*)x0;

    // ---- phase 1: zero va rows 8-15 (dwords [4128,8256)); stage f as bf16;
    // issue v loads early (written to LDS after the FU-GEMM barrier, T14).
    {
        unsigned* z = (unsigned*)smem;
        for (int i = tid; i < 4128; i += 512) z[4128 + i] = 0u;
    }
    float4 vv[4];
#pragma unroll
    for (int p = 0; p < 4; p++) {
        int idx = tid + p * 512;        // 0..2047
        int row = idx >> 8, c4 = idx & 255;
        long g = (long)(row0 + row) * 256 + c4;
        float4 ff = f44[g];
        vv[p] = v04[g];
        short4v sf;
        sf[0] = (short)f2bf(ff.x); sf[1] = (short)f2bf(ff.y);
        sf[2] = (short)f2bf(ff.z); sf[3] = (short)f2bf(ff.w);
        *(short4v*)&va[row][c4 * 4] = sf;
    }
    __syncthreads();

    // ---- phase 2: FU = f@U ; wave owns nt = w and w+8
    floatx4 FU0 = {0.f,0.f,0.f,0.f}, FU1 = {0.f,0.f,0.f,0.f};
#pragma unroll 4
    for (int kt = 0; kt < 32; kt++) {
        short8 a  = *(const short8*)&va[nl][kt * 32 + quad * 8];
        short8 b0 = Up[(kt * 16 + w) * 64 + lane];
        short8 b1 = Up[(kt * 16 + w + 8) * 64 + lane];
        FU0 = __builtin_amdgcn_mfma_f32_16x16x32_bf16(a, b0, FU0, 0, 0, 0);
        FU1 = __builtin_amdgcn_mfma_f32_16x16x32_bf16(a, b1, FU1, 0, 0, 0);
    }
    __syncthreads();   // all f reads done

    // ---- phase 3: stage v (from regs)
#pragma unroll
    for (int p = 0; p < 4; p++) {
        int idx = tid + p * 512;
        int row = idx >> 8, c4 = idx & 255;
        short4v sv;
        sv[0] = (short)f2bf(vv[p].x); sv[1] = (short)f2bf(vv[p].y);
        sv[2] = (short)f2bf(vv[p].z); sv[3] = (short)f2bf(vv[p].w);
        *(short4v*)&va[row][c4 * 4] = sv;
    }
    __syncthreads();

    // ---- wu fragments for both columns -> registers (persist through steps)
    short8 wu0[8], wu1[8];
#pragma unroll
    for (int kt = 0; kt < 8; kt++) {
        wu0[kt] = WUp[(kt * 16 + w) * 64 + lane];
        wu1[kt] = WUp[(kt * 16 + w + 8) * 64 + lane];
    }

    // ---- phase 4: P = v0@U
    floatx4 P0 = {0.f,0.f,0.f,0.f}, P1 = {0.f,0.f,0.f,0.f};
#pragma unroll 4
    for (int kt = 0; kt < 32; kt++) {
        short8 a  = *(const short8*)&va[nl][kt * 32 + quad * 8];
        short8 b0 = Up[(kt * 16 + w) * 64 + lane];
        short8 b1 = Up[(kt * 16 + w + 8) * 64 + lane];
        P0 = __builtin_amdgcn_mfma_f32_16x16x32_bf16(a, b0, P0, 0, 0, 0);
        P1 = __builtin_amdgcn_mfma_f32_16x16x32_bf16(a, b1, P1, 0, 0, 0);
    }
    // no barrier needed: step-0's barrier A covers the last va readers.

    // ---- phase 5: step recurrence; single p^2 buffer, 2 barriers/step
    floatx4 A10 = {0.f,0.f,0.f,0.f}, A11 = {0.f,0.f,0.f,0.f};
    floatx4 Q20 = {0.f,0.f,0.f,0.f}, Q21 = {0.f,0.f,0.f,0.f};
    for (int s = 0; s < steps; s++) {
        float wgt = (float)(steps - 1 - s);
#pragma unroll
        for (int r = 0; r < 4; r++) {
            float g0 = P0[r] * P0[r];
            float g1 = P1[r] * P1[r];
            A10[r] += g0; Q20[r] += wgt * g0;
            A11[r] += g1; Q21[r] += wgt * g1;
            q1[4 * quad + r][16 * w + nl]       = (short)f2bf(g0);
            q1[4 * quad + r][16 * (w + 8) + nl] = (short)f2bf(g1);
        }
        __syncthreads();   // A: p^2 visible
        floatx4 acc0 = {0.f,0.f,0.f,0.f}, acc1 = {0.f,0.f,0.f,0.f};
#pragma unroll
        for (int kt = 0; kt < 8; kt++) {
            short8 a = *(const short8*)&q1[nl][kt * 32 + quad * 8];
            acc0 = __builtin_amdgcn_mfma_f32_16x16x32_bf16(a, wu0[kt], acc0, 0, 0, 0);
            acc1 = __builtin_amdgcn_mfma_f32_16x16x32_bf16(a, wu1[kt], acc1, 0, 0, 0);
        }
#pragma unroll
        for (int r = 0; r < 4; r++) {
            P0[r] += DT * (FU0[r] - acc0[r]);
            P1[r] += DT * (FU1[r] - acc1[r]);
        }
        __syncthreads();   // B: reads done before next write / Q overwrite
    }

    // ---- phase 6: write Q1, Q2 (both columns)
#pragma unroll
    for (int r = 0; r < 4; r++) {
        q1[4 * quad + r][16 * w + nl]       = (short)f2bf(A10[r]);
        q1[4 * quad + r][16 * (w + 8) + nl] = (short)f2bf(A11[r]);
        q2[4 * quad + r][16 * w + nl]       = (short)f2bf(Q20[r]);
        q2[4 * quad + r][16 * (w + 8) + nl] = (short)f2bf(Q21[r]);
    }
    __syncthreads();

    // ---- phase 7: final GEMMs; wave owns nt = 8w..8w+7
    floatx4 y1[8], y2[8];
#pragma unroll
    for (int t = 0; t < 8; t++) {
        y1[t] = (floatx4){0.f,0.f,0.f,0.f};
        y2[t] = (floatx4){0.f,0.f,0.f,0.f};
    }
#pragma unroll 2
    for (int kt = 0; kt < 8; kt++) {
        short8 a1 = *(const short8*)&q1[nl][kt * 32 + quad * 8];
        short8 a2 = *(const short8*)&q2[nl][kt * 32 + quad * 8];
#pragma unroll
        for (int t = 0; t < 8; t++) {
            short8 b = Wp[(kt * 64 + 8 * w + t) * 64 + lane];
            y1[t] = __builtin_amdgcn_mfma_f32_16x16x32_bf16(a1, b, y1[t], 0, 0, 0);
            y2[t] = __builtin_amdgcn_mfma_f32_16x16x32_bf16(a2, b, y2[t], 0, 0, 0);
        }
    }

    // ---- phase 8: 2-pass epilogue via s f32 [8][1032] aliasing A-region
    // (va dead since phase 4; q untouched by s). Real rows live in quads 0,1.
    float (*sst)[1032] = (float(*)[1032])smem;
    float4* out4 = (float4*)out;
#pragma unroll
    for (int sel = 0; sel < 2; sel++) {          // 0: cx term, 1: cv term
        if (quad < 2) {
#pragma unroll
            for (int t = 0; t < 8; t++) {
                int col = 128 * w + 16 * t + nl;
#pragma unroll
                for (int r = 0; r < 4; r++) {
                    int row = 4 * quad + r;      // 0..7
                    sst[row][col] = sel ? (-DT * y1[t][r])
                                        : (-DT * DT * y2[t][r]);
                }
            }
        }
        __syncthreads();
#pragma unroll
        for (int p = 0; p < 4; p++) {
            int idx = tid + p * 512;
            int row = idx >> 8, c4 = idx & 255;
            long gi = (long)(row0 + row) * 256 + c4;
            float4 t = *(const float4*)&sst[row][c4 * 4];
            float4 ff = f44[gi];
            float4 vq = v04[gi];
            float4 o;
            if (sel == 0) {
                float4 xx = x4[gi];
                o.x = xx.x + sdt * vq.x + tdt2 * ff.x + t.x;
                o.y = xx.y + sdt * vq.y + tdt2 * ff.y + t.y;
                o.z = xx.z + sdt * vq.z + tdt2 * ff.z + t.z;
                o.w = xx.w + sdt * vq.w + tdt2 * ff.w + t.w;
                out4[gi] = o;
            } else {
                o.x = vq.x + sdt * ff.x + t.x;
                o.y = vq.y + sdt * ff.y + t.y;
                o.z = vq.z + sdt * ff.z + t.z;
                o.w = vq.w + sdt * ff.w + t.w;
                out4[(long)BB * 256 + gi] = o;
            }
        }
        __syncthreads();   // before next stage overwrites s
    }
}

extern "C" void kernel_launch(void* const* d_in, const int* in_sizes, int n_in,
                              void* d_out, int out_size, void* d_ws, size_t ws_size,
                              hipStream_t stream) {
    const float* x     = (const float*)d_in[0];
    const float* v     = (const float*)d_in[1];
    const float* force = (const float*)d_in[2];
    const float* U     = (const float*)d_in[3];
    const float* W     = (const float*)d_in[4];
    const int*   steps = (const int*)d_in[5];

    short* Up  = (short*)d_ws;                // 262144 shorts = 512 KB
    short* Wp  = Up + 262144;                 // 512 KB
    short* WUp = Wp + 262144;                 // 128 KB

    pack_kernel<<<384, 1024, 0, stream>>>(U, W, Up, Wp, WUp);
    euler_kernel<<<512, 512, 0, stream>>>(x, v, force,
                                          (const short8*)Up, (const short8*)Wp,
                                          (const short8*)WUp,
                                          steps, (float*)d_out);
}